// Round 17
// baseline (365.887 us; speedup 1.0000x reference)
//
#include <hip/hip_runtime.h>
#include <math.h>

// B=4 D=32 N=768 L=192 d_model=128 pred_len=24 in_dim=3
#define NN 768
#define DM 128
#define LL 192
#define BD 128
#define OUT_OFF_A   221184
#define OUT_OFF_GEO 75718656

// ws layout (f32 element offsets):
//  geoS: f32 [768][768]                           [51200, 641024)
//  wh  : bf16 [3][128][192] = 73728 u16           [641024, 677888)
//  w1h : bf16 [32][128] = 4096 u16                [677888, 679936)
//  qh : bf16 [98304][128]                         [739328, 7030784)
//  kh : bf16 [98304][128]                         [7030784, 13322240)
//  vT : bf16 [128][128][768]                      [13322240, 19613696)
//  o1 : f32 [4][768][32][24] = 2,359,296          [19613696, 21972992)
#define WS_CN   16
#define WS_NV1  2048
#define WS_NV2  26624
#define WS_GEOS 51200
#define WS_WH   641024
#define WS_W1H  677888
#define WS_QH   739328
#define WS_KH   7030784
#define WS_VT   13322240
#define WS_O1   19613696

constexpr float TEMP_INV    = 20.0f;                  // 1/0.05
constexpr float QK_SCALE    = 0.08838834764831845f;   // 1/sqrt(128)
constexpr float LOG2E       = 1.4426950408889634f;
constexpr float GS_SCALE    = QK_SCALE * TEMP_INV * LOG2E;

typedef unsigned short u16;
typedef u16 u16x8 __attribute__((ext_vector_type(8)));
typedef u16 u16x4 __attribute__((ext_vector_type(4)));
typedef __bf16 bf16x8 __attribute__((ext_vector_type(8)));
typedef float f32x4 __attribute__((ext_vector_type(4)));

__device__ __forceinline__ u16 f2b(float f) {   // f32 -> bf16 RNE
  unsigned u = __builtin_bit_cast(unsigned, f);
  return (u16)((u + 0x7fffu + ((u >> 16) & 1u)) >> 16);
}

// LDS barrier WITHOUT the vmcnt(0) drain __syncthreads would emit.
__device__ __forceinline__ void lds_barrier() {
  asm volatile("s_waitcnt lgkmcnt(0)" ::: "memory");
  __builtin_amdgcn_s_barrier();
}

// ---------------- kernel 0: block 0 = min/max+csta_n; blocks 1..76 = weight cvt ----------------
__global__ __launch_bounds__(256) void k_prepcvt(const float* __restrict__ cpan,
                                                 const float* __restrict__ csta,
                                                 float* __restrict__ ws,
                                                 const float* __restrict__ Wq, const float* __restrict__ Wk,
                                                 const float* __restrict__ Wv, const float* __restrict__ W_fc1,
                                                 u16* __restrict__ wh, u16* __restrict__ w1h) {
  int t = threadIdx.x;
  if (blockIdx.x != 0) {
    int i = ((blockIdx.x - 1) * 256 + t) * 4;   // 76 blocks: 73728 wqkv + 4096 w1h
    if (i < 73728) {
      const float* src = (i < 24576) ? (Wq + i) : ((i < 49152) ? (Wk + i - 24576) : (Wv + i - 49152));
      float4 v = *(const float4*)src;
      u16x4 o = {f2b(v.x), f2b(v.y), f2b(v.z), f2b(v.w)};
      *(u16x4*)(wh + i) = o;
    } else {
      int j = i - 73728;           // 0..4095: W1h [32][128], rows >=24 zero
      if (j < 4096) {
        int row = j >> 7;
        u16x4 o = {0, 0, 0, 0};
        if (row < 24) {
          float4 v = *(const float4*)(W_fc1 + (size_t)row * 128 + (j & 127));
          o.x = f2b(v.x); o.y = f2b(v.y); o.z = f2b(v.z); o.w = f2b(v.w);
        }
        *(u16x4*)(w1h + j) = o;
      }
    }
    return;
  }
  __shared__ float red[4][4];
  float mnla = 1e30f, mxla = -1e30f, mnlo = 1e30f, mxlo = -1e30f;
  for (int i = t; i < 3072; i += 256) {
    float la = cpan[i * 2 + 0], lo = cpan[i * 2 + 1];
    mnla = fminf(mnla, la); mxla = fmaxf(mxla, la);
    mnlo = fminf(mnlo, lo); mxlo = fmaxf(mxlo, lo);
  }
  for (int off = 1; off < 64; off <<= 1) {
    mnla = fminf(mnla, __shfl_xor(mnla, off));
    mxla = fmaxf(mxla, __shfl_xor(mxla, off));
    mnlo = fminf(mnlo, __shfl_xor(mnlo, off));
    mxlo = fmaxf(mxlo, __shfl_xor(mxlo, off));
  }
  if ((t & 63) == 0) {
    int w = t >> 6;
    red[0][w] = mnla; red[1][w] = mxla; red[2][w] = mnlo; red[3][w] = mxlo;
  }
  __syncthreads();
  mnla = fminf(fminf(red[0][0], red[0][1]), fminf(red[0][2], red[0][3]));
  mxla = fmaxf(fmaxf(red[1][0], red[1][1]), fmaxf(red[1][2], red[1][3]));
  mnlo = fminf(fminf(red[2][0], red[2][1]), fminf(red[2][2], red[2][3]));
  mxlo = fmaxf(fmaxf(red[3][0], red[3][1]), fmaxf(red[3][2], red[3][3]));
  float rla = mxla - mnla + 1e-8f;
  float rlo = mxlo - mnlo + 1e-8f;
  float* cn = ws + WS_CN;
  for (int i = t; i < NN; i += 256) {
    cn[i * 2 + 0] = (csta[i * 2 + 0] - mnla) / rla;
    cn[i * 2 + 1] = (csta[i * 2 + 1] - mnlo) / rlo;
  }
}

// ---------------- kernel 1: node vectors nv1/nv2 ----------------
__global__ __launch_bounds__(64) void k_nodes(const float* __restrict__ cn,
                                              const float* __restrict__ W_sta, const float* __restrict__ b_sta,
                                              const float* __restrict__ W_n1, const float* __restrict__ b_n1,
                                              const float* __restrict__ W_n2, const float* __restrict__ b_n2,
                                              float* __restrict__ nv1, float* __restrict__ nv2) {
  __shared__ float node_c[96];
  int i = blockIdx.x, t = threadIdx.x;
  float c0 = cn[i * 2 + 0], c1 = cn[i * 2 + 1];
  if (t < 32) {
    float nv = c0 * W_sta[t * 2 + 0] + c1 * W_sta[t * 2 + 1] + b_sta[t];
    node_c[t] = sinf(nv);
    node_c[32 + t] = cosf(nv);
    node_c[64 + t] = nv;
  }
  __syncthreads();
  int half = t >> 5, o = t & 31;
  const float* W = half ? W_n2 : W_n1;
  const float* b = half ? b_n2 : b_n1;
  float acc = b[o];
  for (int j = 0; j < 96; ++j) acc = fmaf(node_c[j], W[o * 96 + j], acc);
  acc = fmaxf(acc, 0.0f);
  float ss = acc * acc;
  for (int off = 1; off < 32; off <<= 1) ss += __shfl_xor(ss, off);
  float nrm = fmaxf(sqrtf(ss), 1e-12f);
  (half ? nv2 : nv1)[i * 32 + o] = acc / nrm;
}

// ---------------- kernel 2: geo graph (+ pre-scaled copy) ----------------
__global__ __launch_bounds__(256) void k_geo(const float* __restrict__ nv1, const float* __restrict__ nv2,
                                             const float* __restrict__ cn, const float* __restrict__ dsc_in,
                                             float* __restrict__ geo, float* __restrict__ geoS) {
  int idx = blockIdx.x * 256 + threadIdx.x;
  if (idx >= NN * NN) return;
  int i = idx / NN, j = idx % NN;
  float d1 = 0.f, d2 = 0.f;
  for (int o = 0; o < 32; ++o) {
    d1 = fmaf(nv1[i * 32 + o], nv2[j * 32 + o], d1);
    d2 = fmaf(nv1[j * 32 + o], nv2[i * 32 + o], d2);
  }
  float dla = cn[i * 2] - cn[j * 2], dlo = cn[i * 2 + 1] - cn[j * 2 + 1];
  float dist = sqrtf(dla * dla + dlo * dlo + 1e-8f);
  float x = dsc_in[0];
  float dscale = (1.0f / (1.0f + expf(-x))) * 3.0f;
  float dsim = expf(-dist * dscale);
  float g = 0.3f * (d1 + d2) + 0.4f * dsim + 0.05f;   // always >= 0.05: mask is dead
  geo[idx] = g;
  geoS[idx] = g * GS_SCALE;
}

// ---------------- QKV projection: ONE block does z=0,1,2 (x staged once) ----------------
__global__ __launch_bounds__(256) void k_qkv(const float* __restrict__ x, const u16* __restrict__ wh,
      const float* __restrict__ bq, const float* __restrict__ bk, const float* __restrict__ bv,
      u16* __restrict__ qo, u16* __restrict__ ko, u16* __restrict__ vTo) {
  __shared__ u16 xs[128 * 192];                  // 48 KB
  int m0 = blockIdx.x * 128;
  int t = threadIdx.x;
  const float* xg = x + (size_t)m0 * 192;
  for (int i = t; i < 3072; i += 256) {          // 16B chunks: 128 rows x 24
    int row = i / 24, c = i % 24;
    float4 f0 = *(const float4*)(xg + (size_t)row * 192 + c * 8);
    float4 f1 = *(const float4*)(xg + (size_t)row * 192 + c * 8 + 4);
    u16x8 v8 = {f2b(f0.x), f2b(f0.y), f2b(f0.z), f2b(f0.w),
                f2b(f1.x), f2b(f1.y), f2b(f1.z), f2b(f1.w)};
    int byte = (row * 384 + c * 16) ^ ((row & 7) << 4);
    *(u16x8*)((char*)xs + byte) = v8;
  }
  __syncthreads();
  int w = t >> 6, l = t & 63, wr = w >> 1, wc = w & 1, lg = l >> 4, lm = l & 15;

  auto compute = [&](const u16* W, f32x4 (&acc)[4][4]) {
#pragma unroll
    for (int kk = 0; kk < 6; ++kk) {
      bf16x8 a[4], b[4];
#pragma unroll
      for (int fr = 0; fr < 4; ++fr) {
        int row = wr * 64 + fr * 16 + lm;
        int byte = (row * 384 + kk * 64 + lg * 16) ^ ((row & 7) << 4);
        a[fr] = __builtin_bit_cast(bf16x8, *(const u16x8*)((const char*)xs + byte));
      }
#pragma unroll
      for (int fc = 0; fc < 4; ++fc) {
        int row = wc * 64 + fc * 16 + lm;
        b[fc] = __builtin_bit_cast(bf16x8, *(const u16x8*)(W + row * 192 + kk * 32 + lg * 8));
      }
#pragma unroll
      for (int fr = 0; fr < 4; ++fr)
#pragma unroll
        for (int fc = 0; fc < 4; ++fc)
          acc[fr][fc] = __builtin_amdgcn_mfma_f32_16x16x32_bf16(a[fr], b[fc], acc[fr][fc], 0, 0, 0);
    }
  };

  // z = 0 (q) and z = 1 (k): row-major bf16 out
  for (int z = 0; z < 2; ++z) {
    f32x4 acc[4][4] = {};
    compute(wh + z * 24576, acc);
    const float* bias = z == 0 ? bq : bk;
    u16* out = z == 0 ? qo : ko;
#pragma unroll
    for (int fr = 0; fr < 4; ++fr)
#pragma unroll
      for (int fc = 0; fc < 4; ++fc) {
        int col = wc * 64 + fc * 16 + lm;
        float bb = bias[col];
#pragma unroll
        for (int r = 0; r < 4; ++r) {
          int row = m0 + wr * 64 + fr * 16 + lg * 4 + r;
          out[(size_t)row * 128 + col] = f2b(acc[fr][fc][r] + bb);
        }
      }
  }
  // z = 2 (v): transpose to vT via LDS (xs dead after last MFMA read)
  {
    f32x4 acc[4][4] = {};
    compute(wh + 2 * 24576, acc);
    u16* es = xs;   // reuse: 128*132 = 16896 u16
    __syncthreads();
#pragma unroll
    for (int fr = 0; fr < 4; ++fr)
#pragma unroll
      for (int fc = 0; fc < 4; ++fc) {
        int col = wc * 64 + fc * 16 + lm;
        float bb = bv[col];
#pragma unroll
        for (int r = 0; r < 4; ++r) {
          int row = wr * 64 + fr * 16 + lg * 4 + r;
          es[row * 132 + col] = f2b(acc[fr][fc][r] + bb);
        }
      }
    __syncthreads();
    int col = t >> 1, half = t & 1;
    int bd = m0 / NN, ml = m0 % NN;
    u16* dst = vTo + (size_t)bd * 98304 + (size_t)col * NN + ml + half * 64;
#pragma unroll
    for (int i = 0; i < 64; i += 8) {
      u16x8 v8;
#pragma unroll
      for (int j = 0; j < 8; ++j) v8[j] = es[(half * 64 + i + j) * 132 + col];
      *(u16x8*)(dst + i) = v8;
    }
  }
}

// ---------------- fused attention + fc1: two-pass recompute, dbuf KVBLK=32, setprio on MFMA ----
__global__ __launch_bounds__(256, 4) void k_attn(const u16* __restrict__ qh, const u16* __restrict__ kh,
                                                 const u16* __restrict__ vT, const float* __restrict__ geoS,
                                                 const u16* __restrict__ w1h, const float* __restrict__ b_fc1,
                                                 float* __restrict__ Aout, float* __restrict__ o1) {
  int bd = blockIdx.x;
  int m0 = blockIdx.y * 64;
  __shared__ u16 ks[2][32 * 128];   // 2 x 8 KB (epilogue: reused for t-tiles)
  __shared__ u16 vs[2][128 * 32];   // 2 x 8 KB
  __shared__ u16 pb[4][16 * 32];    // 4 KB per-wave p slices
  int t = threadIdx.x, w = t >> 6, l = t & 63, lm = l & 15, hi = l >> 4;
  const u16* qg = qh + ((size_t)bd * NN + m0) * 128;
  const u16* kg = kh + (size_t)bd * 98304;
  const u16* vg = vT + (size_t)bd * 98304;
  float* Ab = Aout + (size_t)bd * 589824 + (size_t)m0 * NN;
  const float* gb = geoS + (size_t)m0 * NN;

  bf16x8 qf[4];
#pragma unroll
  for (int kk = 0; kk < 4; ++kk)
    qf[kk] = __builtin_bit_cast(bf16x8,
        *(const u16x8*)(qg + (size_t)(w * 16 + lm) * 128 + kk * 32 + hi * 8));

  // ---- pass 1: row sums ----
#pragma unroll
  for (int i = 0; i < 2; ++i) {
    int idx = i * 256 + t, row = idx >> 4, cc = idx & 15;
    u16x8 v8 = *(const u16x8*)(kg + (size_t)row * 128 + cc * 8);
    int byte = (row * 256 + cc * 16) ^ ((row & 7) << 4);
    *(u16x8*)((char*)ks[0] + byte) = v8;
  }
  float gcur[2][4];
#pragma unroll
  for (int fc = 0; fc < 2; ++fc)
#pragma unroll
    for (int r = 0; r < 4; ++r)
      gcur[fc][r] = gb[(size_t)(w * 16 + hi * 4 + r) * NN + fc * 16 + lm];
  lds_barrier();
  float psum[4] = {0.f, 0.f, 0.f, 0.f};
  for (int c = 0; c < 24; ++c) {
    u16x8 kpre[2];
    float gnxt[2][4];
    if (c < 23) {
#pragma unroll
      for (int i = 0; i < 2; ++i) {
        int idx = i * 256 + t, row = idx >> 4, cc = idx & 15;
        kpre[i] = *(const u16x8*)(kg + (size_t)((c + 1) * 32 + row) * 128 + cc * 8);
      }
#pragma unroll
      for (int fc = 0; fc < 2; ++fc)
#pragma unroll
        for (int r = 0; r < 4; ++r)
          gnxt[fc][r] = gb[(size_t)(w * 16 + hi * 4 + r) * NN + (c + 1) * 32 + fc * 16 + lm];
    }
    const u16* kb = ks[c & 1];
    f32x4 acc[2] = {};
    __builtin_amdgcn_s_setprio(1);
#pragma unroll
    for (int kk = 0; kk < 4; ++kk)
#pragma unroll
      for (int fc = 0; fc < 2; ++fc) {
        int row = fc * 16 + lm;
        int byte = (row * 256 + kk * 64 + hi * 16) ^ ((row & 7) << 4);
        bf16x8 b = __builtin_bit_cast(bf16x8, *(const u16x8*)((const char*)kb + byte));
        acc[fc] = __builtin_amdgcn_mfma_f32_16x16x32_bf16(qf[kk], b, acc[fc], 0, 0, 0);
      }
    __builtin_amdgcn_s_setprio(0);
    if (c < 23) {
#pragma unroll
      for (int i = 0; i < 2; ++i) {
        int idx = i * 256 + t, row = idx >> 4, cc = idx & 15;
        int byte = (row * 256 + cc * 16) ^ ((row & 7) << 4);
        *(u16x8*)((char*)ks[(c + 1) & 1] + byte) = kpre[i];
      }
    }
#pragma unroll
    for (int fc = 0; fc < 2; ++fc)
#pragma unroll
      for (int r = 0; r < 4; ++r)
        psum[r] += __builtin_amdgcn_exp2f(fminf(acc[fc][r] * gcur[fc][r], 120.0f));
    if (c < 23) {
#pragma unroll
      for (int fc = 0; fc < 2; ++fc)
#pragma unroll
        for (int r = 0; r < 4; ++r) gcur[fc][r] = gnxt[fc][r];
    }
    lds_barrier();
  }
#pragma unroll
  for (int off = 1; off < 16; off <<= 1)
#pragma unroll
    for (int r = 0; r < 4; ++r) psum[r] += __shfl_xor(psum[r], off);
  float inv[4];
#pragma unroll
  for (int r = 0; r < 4; ++r) inv[r] = 1.0f / psum[r];

  // ---- pass 2: recompute (bit-identical), write A once (nontemporal), PV ----
#pragma unroll
  for (int i = 0; i < 2; ++i) {
    int idx = i * 256 + t;
    int krow = idx >> 4, kcc = idx & 15;
    u16x8 kv8 = *(const u16x8*)(kg + (size_t)krow * 128 + kcc * 8);
    int kbyte = (krow * 256 + kcc * 16) ^ ((krow & 7) << 4);
    *(u16x8*)((char*)ks[0] + kbyte) = kv8;
    int vrow = idx >> 2, vcc = idx & 3;
    u16x8 vv8 = *(const u16x8*)(vg + (size_t)vrow * NN + vcc * 8);
    int vbyte = (vrow * 64 + vcc * 16) ^ ((vrow & 7) << 4);
    *(u16x8*)((char*)vs[0] + vbyte) = vv8;
  }
  float g2[2][4];
#pragma unroll
  for (int fc = 0; fc < 2; ++fc)
#pragma unroll
    for (int r = 0; r < 4; ++r)
      g2[fc][r] = gb[(size_t)(w * 16 + hi * 4 + r) * NN + fc * 16 + lm];
  lds_barrier();
  f32x4 tacc[8] = {};
  u16* pw = pb[w];
  for (int c = 0; c < 24; ++c) {
    u16x8 kpre[2], vpre[2];
    float gnxt[2][4];
    if (c < 23) {
#pragma unroll
      for (int i = 0; i < 2; ++i) {
        int idx = i * 256 + t;
        int krow = idx >> 4, kcc = idx & 15;
        kpre[i] = *(const u16x8*)(kg + (size_t)((c + 1) * 32 + krow) * 128 + kcc * 8);
        int vrow = idx >> 2, vcc = idx & 3;
        vpre[i] = *(const u16x8*)(vg + (size_t)vrow * NN + (c + 1) * 32 + vcc * 8);
      }
#pragma unroll
      for (int fc = 0; fc < 2; ++fc)
#pragma unroll
        for (int r = 0; r < 4; ++r)
          gnxt[fc][r] = gb[(size_t)(w * 16 + hi * 4 + r) * NN + (c + 1) * 32 + fc * 16 + lm];
    }
    const u16* kb = ks[c & 1];
    f32x4 acc[2] = {};
    __builtin_amdgcn_s_setprio(1);
#pragma unroll
    for (int kk = 0; kk < 4; ++kk)
#pragma unroll
      for (int fc = 0; fc < 2; ++fc) {
        int row = fc * 16 + lm;
        int byte = (row * 256 + kk * 64 + hi * 16) ^ ((row & 7) << 4);
        bf16x8 b = __builtin_bit_cast(bf16x8, *(const u16x8*)((const char*)kb + byte));
        acc[fc] = __builtin_amdgcn_mfma_f32_16x16x32_bf16(qf[kk], b, acc[fc], 0, 0, 0);
      }
    __builtin_amdgcn_s_setprio(0);
    if (c < 23) {
#pragma unroll
      for (int i = 0; i < 2; ++i) {
        int idx = i * 256 + t;
        int krow = idx >> 4, kcc = idx & 15;
        int kbyte = (krow * 256 + kcc * 16) ^ ((krow & 7) << 4);
        *(u16x8*)((char*)ks[(c + 1) & 1] + kbyte) = kpre[i];
        int vrow = idx >> 2, vcc = idx & 3;
        int vbyte = (vrow * 64 + vcc * 16) ^ ((vrow & 7) << 4);
        *(u16x8*)((char*)vs[(c + 1) & 1] + vbyte) = vpre[i];
      }
    }
    // epilogue: u = exp2(acc*gS) (identical to pass 1), p = u*inv, A nontemporal, p->LDS
#pragma unroll
    for (int fc = 0; fc < 2; ++fc) {
      int col = c * 32 + fc * 16 + lm;
#pragma unroll
      for (int r = 0; r < 4; ++r) {
        int rl = w * 16 + hi * 4 + r;
        float u = __builtin_amdgcn_exp2f(fminf(acc[fc][r] * g2[fc][r], 120.0f));
        float p = u * inv[r];
        __builtin_nontemporal_store(p, Ab + (size_t)rl * NN + col);
        int rloc = hi * 4 + r;
        int byte = (rloc * 64 + (fc * 16 + lm) * 2) ^ ((rloc & 7) << 4);
        *(u16*)((char*)pw + byte) = f2b(p);
      }
    }
    if (c < 23) {
#pragma unroll
      for (int fc = 0; fc < 2; ++fc)
#pragma unroll
        for (int r = 0; r < 4; ++r) g2[fc][r] = gnxt[fc][r];
    }
    bf16x8 pa;
    {
      int byte = (lm * 64 + hi * 16) ^ ((lm & 7) << 4);
      pa = __builtin_bit_cast(bf16x8, *(const u16x8*)((const char*)pw + byte));
    }
    const u16* vb = vs[c & 1];
    __builtin_amdgcn_s_setprio(1);
#pragma unroll
    for (int fc = 0; fc < 8; ++fc) {
      int row = fc * 16 + lm;
      int byte = (row * 64 + hi * 16) ^ ((row & 7) << 4);
      bf16x8 b = __builtin_bit_cast(bf16x8, *(const u16x8*)((const char*)vb + byte));
      tacc[fc] = __builtin_amdgcn_mfma_f32_16x16x32_bf16(pa, b, tacc[fc], 0, 0, 0);
    }
    __builtin_amdgcn_s_setprio(0);
    lds_barrier();
  }

  // ---- fc1 fused epilogue: o1[b][n][d][24] = t @ W_fc1^T + b_fc1 (per-wave LDS) ----
  u16* ts = (u16*)ks + w * 2048;   // 4 KB per wave: 16 rows x 128 cols bf16, swizzled
#pragma unroll
  for (int fc = 0; fc < 8; ++fc)
#pragma unroll
    for (int r = 0; r < 4; ++r) {
      int row = hi * 4 + r, col = fc * 16 + lm;
      int byte = (row * 256 + col * 2) ^ ((row & 7) << 4);
      *(u16*)((char*)ts + byte) = f2b(tacc[fc][r]);
    }
  f32x4 of[2] = {};
#pragma unroll
  for (int kk = 0; kk < 4; ++kk) {
    int byte = (lm * 256 + kk * 64 + hi * 16) ^ ((lm & 7) << 4);
    bf16x8 tf = __builtin_bit_cast(bf16x8, *(const u16x8*)((const char*)ts + byte));
#pragma unroll
    for (int g = 0; g < 2; ++g) {
      bf16x8 wf = __builtin_bit_cast(bf16x8,
          *(const u16x8*)(w1h + (size_t)(g * 16 + lm) * 128 + kk * 32 + hi * 8));
      of[g] = __builtin_amdgcn_mfma_f32_16x16x32_bf16(tf, wf, of[g], 0, 0, 0);
    }
  }
  int bi = bd >> 5, di = bd & 31;
#pragma unroll
  for (int g = 0; g < 2; ++g) {
    int pp = g * 16 + lm;
    if (pp < 24) {
      float bb = b_fc1[pp];
#pragma unroll
      for (int r = 0; r < 4; ++r) {
        int n = m0 + w * 16 + hi * 4 + r;
        __builtin_nontemporal_store(of[g][r] + bb,
            o1 + ((size_t)(bi * NN + n) * 32 + di) * 24 + pp);
      }
    }
  }
}

// ---------------- final: fc2 mix over d (o1 contiguous per (b,n)) ----------------
__global__ __launch_bounds__(256) void k_final2(const float* __restrict__ o1, const float* __restrict__ W_fc2,
                                                const float* __restrict__ b_fc2, float* __restrict__ out) {
  __shared__ float ol[2][768];
  __shared__ float w2[96];
  int t = threadIdx.x, half = t >> 7, tl = t & 127;
  int b = blockIdx.x / 384, np = blockIdx.x % 384;
  int n = np * 2 + half;
  const float* src = o1 + (size_t)(b * NN + n) * 768;
  if (t < 96) w2[t] = W_fc2[t];
  for (int i = tl; i < 192; i += 128)
    *(float4*)&ol[half][i * 4] = *(const float4*)(src + i * 4);
  __syncthreads();
  if (tl < 72) {
    int c = tl / 24, pp = tl % 24;
    float acc = b_fc2[c];
#pragma unroll
    for (int d = 0; d < 32; ++d) acc = fmaf(w2[c * 32 + d], ol[half][d * 24 + pp], acc);
    out[(((size_t)b * 3 + c) * NN + n) * 24 + pp] = acc;
  }
}

extern "C" void kernel_launch(void* const* d_in, const int* in_sizes, int n_in,
                              void* d_out, int out_size, void* d_ws, size_t ws_size,
                              hipStream_t stream) {
  (void)in_sizes; (void)n_in; (void)out_size; (void)ws_size;
  const float* x     = (const float*)d_in[1];
  const float* csta  = (const float*)d_in[2];
  const float* cpan  = (const float*)d_in[3];
  const float* Wq    = (const float*)d_in[4];
  const float* bq    = (const float*)d_in[5];
  const float* Wk    = (const float*)d_in[6];
  const float* bk    = (const float*)d_in[7];
  const float* Wv    = (const float*)d_in[8];
  const float* bv    = (const float*)d_in[9];
  const float* W_sta = (const float*)d_in[10];
  const float* b_sta = (const float*)d_in[11];
  const float* W_n1  = (const float*)d_in[12];
  const float* b_n1  = (const float*)d_in[13];
  const float* W_n2  = (const float*)d_in[14];
  const float* b_n2  = (const float*)d_in[15];
  const float* dsc   = (const float*)d_in[16];
  const float* W_fc1 = (const float*)d_in[17];
  const float* b_fc1 = (const float*)d_in[18];
  const float* W_fc2 = (const float*)d_in[19];
  const float* b_fc2 = (const float*)d_in[20];

  float* out  = (float*)d_out;
  float* Aout = out + OUT_OFF_A;
  float* geo  = out + OUT_OFF_GEO;

  float* ws   = (float*)d_ws;
  float* cn   = ws + WS_CN;
  float* nv1  = ws + WS_NV1;
  float* nv2  = ws + WS_NV2;
  float* geoS = ws + WS_GEOS;
  u16*   wh   = (u16*)(ws + WS_WH);
  u16*   w1h  = (u16*)(ws + WS_W1H);
  u16*   qh   = (u16*)(ws + WS_QH);
  u16*   kh   = (u16*)(ws + WS_KH);
  u16*   vT   = (u16*)(ws + WS_VT);
  float* o1   = ws + WS_O1;

  k_prepcvt<<<77, 256, 0, stream>>>(cpan, csta, ws, Wq, Wk, Wv, W_fc1, wh, w1h);
  k_nodes<<<768, 64, 0, stream>>>(cn, W_sta, b_sta, W_n1, b_n1, W_n2, b_n2, nv1, nv2);
  k_geo<<<(NN * NN + 255) / 256, 256, 0, stream>>>(nv1, nv2, cn, dsc, geo, geoS);

  k_qkv<<<768, 256, 0, stream>>>(x, wh, bq, bk, bv, qh, kh, vT);
  k_attn<<<dim3(BD, 12), 256, 0, stream>>>(qh, kh, vT, geoS, w1h, b_fc1, Aout, o1);
  k_final2<<<1536, 256, 0, stream>>>(o1, W_fc2, b_fc2, out);
}

// Round 18
// 251.126 us; speedup vs baseline: 1.4570x; 1.4570x over previous
//
#include <hip/hip_runtime.h>
#include <math.h>

// B=4 D=32 N=768 L=192 d_model=128 pred_len=24 in_dim=3
#define NN 768
#define DM 128
#define LL 192
#define BD 128
#define OUT_OFF_A   221184
#define OUT_OFF_GEO 75718656

// ws layout (f32 element offsets):
//  geoS: f32 [768][768]                           [51200, 641024)
//  wh  : bf16 [3][128][192] = 73728 u16           [641024, 677888)
//  w1h : bf16 [32][128] = 4096 u16                [677888, 679936)
//  qh : bf16 [98304][128]                         [739328, 7030784)
//  kh : bf16 [98304][128]                         [7030784, 13322240)
//  vT : bf16 [128][128][768]                      [13322240, 19613696)
//  o1 : f32 [4][768][32][24] = 2,359,296          [19613696, 21972992)
#define WS_CN   16
#define WS_NV1  2048
#define WS_NV2  26624
#define WS_GEOS 51200
#define WS_WH   641024
#define WS_W1H  677888
#define WS_QH   739328
#define WS_KH   7030784
#define WS_VT   13322240
#define WS_O1   19613696

constexpr float TEMP_INV    = 20.0f;                  // 1/0.05
constexpr float QK_SCALE    = 0.08838834764831845f;   // 1/sqrt(128)
constexpr float LOG2E       = 1.4426950408889634f;
constexpr float GS_SCALE    = QK_SCALE * TEMP_INV * LOG2E;

typedef unsigned short u16;
typedef u16 u16x8 __attribute__((ext_vector_type(8)));
typedef u16 u16x4 __attribute__((ext_vector_type(4)));
typedef __bf16 bf16x8 __attribute__((ext_vector_type(8)));
typedef float f32x4 __attribute__((ext_vector_type(4)));

__device__ __forceinline__ u16 f2b(float f) {   // f32 -> bf16 RNE
  unsigned u = __builtin_bit_cast(unsigned, f);
  return (u16)((u + 0x7fffu + ((u >> 16) & 1u)) >> 16);
}

// LDS barrier WITHOUT the vmcnt(0) drain __syncthreads would emit.
__device__ __forceinline__ void lds_barrier() {
  asm volatile("s_waitcnt lgkmcnt(0)" ::: "memory");
  __builtin_amdgcn_s_barrier();
}

// ---------------- kernel 0: block 0 = min/max+csta_n; blocks 1..76 = weight cvt ----------------
__global__ __launch_bounds__(256) void k_prepcvt(const float* __restrict__ cpan,
                                                 const float* __restrict__ csta,
                                                 float* __restrict__ ws,
                                                 const float* __restrict__ Wq, const float* __restrict__ Wk,
                                                 const float* __restrict__ Wv, const float* __restrict__ W_fc1,
                                                 u16* __restrict__ wh, u16* __restrict__ w1h) {
  int t = threadIdx.x;
  if (blockIdx.x != 0) {
    int i = ((blockIdx.x - 1) * 256 + t) * 4;   // 76 blocks: 73728 wqkv + 4096 w1h
    if (i < 73728) {
      const float* src = (i < 24576) ? (Wq + i) : ((i < 49152) ? (Wk + i - 24576) : (Wv + i - 49152));
      float4 v = *(const float4*)src;
      u16x4 o = {f2b(v.x), f2b(v.y), f2b(v.z), f2b(v.w)};
      *(u16x4*)(wh + i) = o;
    } else {
      int j = i - 73728;           // 0..4095: W1h [32][128], rows >=24 zero
      if (j < 4096) {
        int row = j >> 7;
        u16x4 o = {0, 0, 0, 0};
        if (row < 24) {
          float4 v = *(const float4*)(W_fc1 + (size_t)row * 128 + (j & 127));
          o.x = f2b(v.x); o.y = f2b(v.y); o.z = f2b(v.z); o.w = f2b(v.w);
        }
        *(u16x4*)(w1h + j) = o;
      }
    }
    return;
  }
  __shared__ float red[4][4];
  float mnla = 1e30f, mxla = -1e30f, mnlo = 1e30f, mxlo = -1e30f;
  for (int i = t; i < 3072; i += 256) {
    float la = cpan[i * 2 + 0], lo = cpan[i * 2 + 1];
    mnla = fminf(mnla, la); mxla = fmaxf(mxla, la);
    mnlo = fminf(mnlo, lo); mxlo = fmaxf(mxlo, lo);
  }
  for (int off = 1; off < 64; off <<= 1) {
    mnla = fminf(mnla, __shfl_xor(mnla, off));
    mxla = fmaxf(mxla, __shfl_xor(mxla, off));
    mnlo = fminf(mnlo, __shfl_xor(mnlo, off));
    mxlo = fmaxf(mxlo, __shfl_xor(mxlo, off));
  }
  if ((t & 63) == 0) {
    int w = t >> 6;
    red[0][w] = mnla; red[1][w] = mxla; red[2][w] = mnlo; red[3][w] = mxlo;
  }
  __syncthreads();
  mnla = fminf(fminf(red[0][0], red[0][1]), fminf(red[0][2], red[0][3]));
  mxla = fmaxf(fmaxf(red[1][0], red[1][1]), fmaxf(red[1][2], red[1][3]));
  mnlo = fminf(fminf(red[2][0], red[2][1]), fminf(red[2][2], red[2][3]));
  mxlo = fmaxf(fmaxf(red[3][0], red[3][1]), fmaxf(red[3][2], red[3][3]));
  float rla = mxla - mnla + 1e-8f;
  float rlo = mxlo - mnlo + 1e-8f;
  float* cn = ws + WS_CN;
  for (int i = t; i < NN; i += 256) {
    cn[i * 2 + 0] = (csta[i * 2 + 0] - mnla) / rla;
    cn[i * 2 + 1] = (csta[i * 2 + 1] - mnlo) / rlo;
  }
}

// ---------------- kernel 1: node vectors nv1/nv2 ----------------
__global__ __launch_bounds__(64) void k_nodes(const float* __restrict__ cn,
                                              const float* __restrict__ W_sta, const float* __restrict__ b_sta,
                                              const float* __restrict__ W_n1, const float* __restrict__ b_n1,
                                              const float* __restrict__ W_n2, const float* __restrict__ b_n2,
                                              float* __restrict__ nv1, float* __restrict__ nv2) {
  __shared__ float node_c[96];
  int i = blockIdx.x, t = threadIdx.x;
  float c0 = cn[i * 2 + 0], c1 = cn[i * 2 + 1];
  if (t < 32) {
    float nv = c0 * W_sta[t * 2 + 0] + c1 * W_sta[t * 2 + 1] + b_sta[t];
    node_c[t] = sinf(nv);
    node_c[32 + t] = cosf(nv);
    node_c[64 + t] = nv;
  }
  __syncthreads();
  int half = t >> 5, o = t & 31;
  const float* W = half ? W_n2 : W_n1;
  const float* b = half ? b_n2 : b_n1;
  float acc = b[o];
  for (int j = 0; j < 96; ++j) acc = fmaf(node_c[j], W[o * 96 + j], acc);
  acc = fmaxf(acc, 0.0f);
  float ss = acc * acc;
  for (int off = 1; off < 32; off <<= 1) ss += __shfl_xor(ss, off);
  float nrm = fmaxf(sqrtf(ss), 1e-12f);
  (half ? nv2 : nv1)[i * 32 + o] = acc / nrm;
}

// ---------------- kernel 2: geo graph (+ pre-scaled copy) ----------------
__global__ __launch_bounds__(256) void k_geo(const float* __restrict__ nv1, const float* __restrict__ nv2,
                                             const float* __restrict__ cn, const float* __restrict__ dsc_in,
                                             float* __restrict__ geo, float* __restrict__ geoS) {
  int idx = blockIdx.x * 256 + threadIdx.x;
  if (idx >= NN * NN) return;
  int i = idx / NN, j = idx % NN;
  float d1 = 0.f, d2 = 0.f;
  for (int o = 0; o < 32; ++o) {
    d1 = fmaf(nv1[i * 32 + o], nv2[j * 32 + o], d1);
    d2 = fmaf(nv1[j * 32 + o], nv2[i * 32 + o], d2);
  }
  float dla = cn[i * 2] - cn[j * 2], dlo = cn[i * 2 + 1] - cn[j * 2 + 1];
  float dist = sqrtf(dla * dla + dlo * dlo + 1e-8f);
  float x = dsc_in[0];
  float dscale = (1.0f / (1.0f + expf(-x))) * 3.0f;
  float dsim = expf(-dist * dscale);
  float g = 0.3f * (d1 + d2) + 0.4f * dsim + 0.05f;   // always >= 0.05: mask is dead
  geo[idx] = g;
  geoS[idx] = g * GS_SCALE;
}

// ---------------- QKV projection: ONE block does z=0,1,2 (x staged once) ----------------
__global__ __launch_bounds__(256) void k_qkv(const float* __restrict__ x, const u16* __restrict__ wh,
      const float* __restrict__ bq, const float* __restrict__ bk, const float* __restrict__ bv,
      u16* __restrict__ qo, u16* __restrict__ ko, u16* __restrict__ vTo) {
  __shared__ u16 xs[128 * 192];                  // 48 KB
  int m0 = blockIdx.x * 128;
  int t = threadIdx.x;
  const float* xg = x + (size_t)m0 * 192;
  for (int i = t; i < 3072; i += 256) {          // 16B chunks: 128 rows x 24
    int row = i / 24, c = i % 24;
    float4 f0 = *(const float4*)(xg + (size_t)row * 192 + c * 8);
    float4 f1 = *(const float4*)(xg + (size_t)row * 192 + c * 8 + 4);
    u16x8 v8 = {f2b(f0.x), f2b(f0.y), f2b(f0.z), f2b(f0.w),
                f2b(f1.x), f2b(f1.y), f2b(f1.z), f2b(f1.w)};
    int byte = (row * 384 + c * 16) ^ ((row & 7) << 4);
    *(u16x8*)((char*)xs + byte) = v8;
  }
  __syncthreads();
  int w = t >> 6, l = t & 63, wr = w >> 1, wc = w & 1, lg = l >> 4, lm = l & 15;

  auto compute = [&](const u16* W, f32x4 (&acc)[4][4]) {
#pragma unroll
    for (int kk = 0; kk < 6; ++kk) {
      bf16x8 a[4], b[4];
#pragma unroll
      for (int fr = 0; fr < 4; ++fr) {
        int row = wr * 64 + fr * 16 + lm;
        int byte = (row * 384 + kk * 64 + lg * 16) ^ ((row & 7) << 4);
        a[fr] = __builtin_bit_cast(bf16x8, *(const u16x8*)((const char*)xs + byte));
      }
#pragma unroll
      for (int fc = 0; fc < 4; ++fc) {
        int row = wc * 64 + fc * 16 + lm;
        b[fc] = __builtin_bit_cast(bf16x8, *(const u16x8*)(W + row * 192 + kk * 32 + lg * 8));
      }
#pragma unroll
      for (int fr = 0; fr < 4; ++fr)
#pragma unroll
        for (int fc = 0; fc < 4; ++fc)
          acc[fr][fc] = __builtin_amdgcn_mfma_f32_16x16x32_bf16(a[fr], b[fc], acc[fr][fc], 0, 0, 0);
    }
  };

  // z = 0 (q) and z = 1 (k): row-major bf16 out
  for (int z = 0; z < 2; ++z) {
    f32x4 acc[4][4] = {};
    compute(wh + z * 24576, acc);
    const float* bias = z == 0 ? bq : bk;
    u16* out = z == 0 ? qo : ko;
#pragma unroll
    for (int fr = 0; fr < 4; ++fr)
#pragma unroll
      for (int fc = 0; fc < 4; ++fc) {
        int col = wc * 64 + fc * 16 + lm;
        float bb = bias[col];
#pragma unroll
        for (int r = 0; r < 4; ++r) {
          int row = m0 + wr * 64 + fr * 16 + lg * 4 + r;
          out[(size_t)row * 128 + col] = f2b(acc[fr][fc][r] + bb);
        }
      }
  }
  // z = 2 (v): transpose to vT via LDS (xs dead after last MFMA read)
  {
    f32x4 acc[4][4] = {};
    compute(wh + 2 * 24576, acc);
    u16* es = xs;   // reuse: 128*132 = 16896 u16
    __syncthreads();
#pragma unroll
    for (int fr = 0; fr < 4; ++fr)
#pragma unroll
      for (int fc = 0; fc < 4; ++fc) {
        int col = wc * 64 + fc * 16 + lm;
        float bb = bv[col];
#pragma unroll
        for (int r = 0; r < 4; ++r) {
          int row = wr * 64 + fr * 16 + lg * 4 + r;
          es[row * 132 + col] = f2b(acc[fr][fc][r] + bb);
        }
      }
    __syncthreads();
    int col = t >> 1, half = t & 1;
    int bd = m0 / NN, ml = m0 % NN;
    u16* dst = vTo + (size_t)bd * 98304 + (size_t)col * NN + ml + half * 64;
#pragma unroll
    for (int i = 0; i < 64; i += 8) {
      u16x8 v8;
#pragma unroll
      for (int j = 0; j < 8; ++j) v8[j] = es[(half * 64 + i + j) * 132 + col];
      *(u16x8*)(dst + i) = v8;
    }
  }
}

// ---------------- fused attention + fc1: two-pass recompute, dbuf KVBLK=32 (r13/r16 version) ----
__global__ __launch_bounds__(256, 4) void k_attn(const u16* __restrict__ qh, const u16* __restrict__ kh,
                                                 const u16* __restrict__ vT, const float* __restrict__ geoS,
                                                 const u16* __restrict__ w1h, const float* __restrict__ b_fc1,
                                                 float* __restrict__ Aout, float* __restrict__ o1) {
  int bd = blockIdx.x;
  int m0 = blockIdx.y * 64;
  __shared__ u16 ks[2][32 * 128];   // 2 x 8 KB (epilogue: reused for t-tiles)
  __shared__ u16 vs[2][128 * 32];   // 2 x 8 KB
  __shared__ u16 pb[4][16 * 32];    // 4 KB per-wave p slices
  int t = threadIdx.x, w = t >> 6, l = t & 63, lm = l & 15, hi = l >> 4;
  const u16* qg = qh + ((size_t)bd * NN + m0) * 128;
  const u16* kg = kh + (size_t)bd * 98304;
  const u16* vg = vT + (size_t)bd * 98304;
  float* Ab = Aout + (size_t)bd * 589824 + (size_t)m0 * NN;
  const float* gb = geoS + (size_t)m0 * NN;

  bf16x8 qf[4];
#pragma unroll
  for (int kk = 0; kk < 4; ++kk)
    qf[kk] = __builtin_bit_cast(bf16x8,
        *(const u16x8*)(qg + (size_t)(w * 16 + lm) * 128 + kk * 32 + hi * 8));

  // ---- pass 1: row sums ----
#pragma unroll
  for (int i = 0; i < 2; ++i) {
    int idx = i * 256 + t, row = idx >> 4, cc = idx & 15;
    u16x8 v8 = *(const u16x8*)(kg + (size_t)row * 128 + cc * 8);
    int byte = (row * 256 + cc * 16) ^ ((row & 7) << 4);
    *(u16x8*)((char*)ks[0] + byte) = v8;
  }
  float gcur[2][4];
#pragma unroll
  for (int fc = 0; fc < 2; ++fc)
#pragma unroll
    for (int r = 0; r < 4; ++r)
      gcur[fc][r] = gb[(size_t)(w * 16 + hi * 4 + r) * NN + fc * 16 + lm];
  lds_barrier();
  float psum[4] = {0.f, 0.f, 0.f, 0.f};
  for (int c = 0; c < 24; ++c) {
    u16x8 kpre[2];
    float gnxt[2][4];
    if (c < 23) {
#pragma unroll
      for (int i = 0; i < 2; ++i) {
        int idx = i * 256 + t, row = idx >> 4, cc = idx & 15;
        kpre[i] = *(const u16x8*)(kg + (size_t)((c + 1) * 32 + row) * 128 + cc * 8);
      }
#pragma unroll
      for (int fc = 0; fc < 2; ++fc)
#pragma unroll
        for (int r = 0; r < 4; ++r)
          gnxt[fc][r] = gb[(size_t)(w * 16 + hi * 4 + r) * NN + (c + 1) * 32 + fc * 16 + lm];
    }
    const u16* kb = ks[c & 1];
    f32x4 acc[2] = {};
#pragma unroll
    for (int kk = 0; kk < 4; ++kk)
#pragma unroll
      for (int fc = 0; fc < 2; ++fc) {
        int row = fc * 16 + lm;
        int byte = (row * 256 + kk * 64 + hi * 16) ^ ((row & 7) << 4);
        bf16x8 b = __builtin_bit_cast(bf16x8, *(const u16x8*)((const char*)kb + byte));
        acc[fc] = __builtin_amdgcn_mfma_f32_16x16x32_bf16(qf[kk], b, acc[fc], 0, 0, 0);
      }
    if (c < 23) {
#pragma unroll
      for (int i = 0; i < 2; ++i) {
        int idx = i * 256 + t, row = idx >> 4, cc = idx & 15;
        int byte = (row * 256 + cc * 16) ^ ((row & 7) << 4);
        *(u16x8*)((char*)ks[(c + 1) & 1] + byte) = kpre[i];
      }
    }
#pragma unroll
    for (int fc = 0; fc < 2; ++fc)
#pragma unroll
      for (int r = 0; r < 4; ++r)
        psum[r] += __builtin_amdgcn_exp2f(fminf(acc[fc][r] * gcur[fc][r], 120.0f));
    if (c < 23) {
#pragma unroll
      for (int fc = 0; fc < 2; ++fc)
#pragma unroll
        for (int r = 0; r < 4; ++r) gcur[fc][r] = gnxt[fc][r];
    }
    lds_barrier();
  }
#pragma unroll
  for (int off = 1; off < 16; off <<= 1)
#pragma unroll
    for (int r = 0; r < 4; ++r) psum[r] += __shfl_xor(psum[r], off);
  float inv[4];
#pragma unroll
  for (int r = 0; r < 4; ++r) inv[r] = 1.0f / psum[r];

  // ---- pass 2: recompute (bit-identical), write A once (nontemporal), PV ----
#pragma unroll
  for (int i = 0; i < 2; ++i) {
    int idx = i * 256 + t;
    int krow = idx >> 4, kcc = idx & 15;
    u16x8 kv8 = *(const u16x8*)(kg + (size_t)krow * 128 + kcc * 8);
    int kbyte = (krow * 256 + kcc * 16) ^ ((krow & 7) << 4);
    *(u16x8*)((char*)ks[0] + kbyte) = kv8;
    int vrow = idx >> 2, vcc = idx & 3;
    u16x8 vv8 = *(const u16x8*)(vg + (size_t)vrow * NN + vcc * 8);
    int vbyte = (vrow * 64 + vcc * 16) ^ ((vrow & 7) << 4);
    *(u16x8*)((char*)vs[0] + vbyte) = vv8;
  }
  float g2[2][4];
#pragma unroll
  for (int fc = 0; fc < 2; ++fc)
#pragma unroll
    for (int r = 0; r < 4; ++r)
      g2[fc][r] = gb[(size_t)(w * 16 + hi * 4 + r) * NN + fc * 16 + lm];
  lds_barrier();
  f32x4 tacc[8] = {};
  u16* pw = pb[w];
  for (int c = 0; c < 24; ++c) {
    u16x8 kpre[2], vpre[2];
    float gnxt[2][4];
    if (c < 23) {
#pragma unroll
      for (int i = 0; i < 2; ++i) {
        int idx = i * 256 + t;
        int krow = idx >> 4, kcc = idx & 15;
        kpre[i] = *(const u16x8*)(kg + (size_t)((c + 1) * 32 + krow) * 128 + kcc * 8);
        int vrow = idx >> 2, vcc = idx & 3;
        vpre[i] = *(const u16x8*)(vg + (size_t)vrow * NN + (c + 1) * 32 + vcc * 8);
      }
#pragma unroll
      for (int fc = 0; fc < 2; ++fc)
#pragma unroll
        for (int r = 0; r < 4; ++r)
          gnxt[fc][r] = gb[(size_t)(w * 16 + hi * 4 + r) * NN + (c + 1) * 32 + fc * 16 + lm];
    }
    const u16* kb = ks[c & 1];
    f32x4 acc[2] = {};
#pragma unroll
    for (int kk = 0; kk < 4; ++kk)
#pragma unroll
      for (int fc = 0; fc < 2; ++fc) {
        int row = fc * 16 + lm;
        int byte = (row * 256 + kk * 64 + hi * 16) ^ ((row & 7) << 4);
        bf16x8 b = __builtin_bit_cast(bf16x8, *(const u16x8*)((const char*)kb + byte));
        acc[fc] = __builtin_amdgcn_mfma_f32_16x16x32_bf16(qf[kk], b, acc[fc], 0, 0, 0);
      }
    if (c < 23) {
#pragma unroll
      for (int i = 0; i < 2; ++i) {
        int idx = i * 256 + t;
        int krow = idx >> 4, kcc = idx & 15;
        int kbyte = (krow * 256 + kcc * 16) ^ ((krow & 7) << 4);
        *(u16x8*)((char*)ks[(c + 1) & 1] + kbyte) = kpre[i];
        int vrow = idx >> 2, vcc = idx & 3;
        int vbyte = (vrow * 64 + vcc * 16) ^ ((vrow & 7) << 4);
        *(u16x8*)((char*)vs[(c + 1) & 1] + vbyte) = vpre[i];
      }
    }
    // epilogue: u = exp2(acc*gS) (identical to pass 1), p = u*inv, A nontemporal, p->LDS
#pragma unroll
    for (int fc = 0; fc < 2; ++fc) {
      int col = c * 32 + fc * 16 + lm;
#pragma unroll
      for (int r = 0; r < 4; ++r) {
        int rl = w * 16 + hi * 4 + r;
        float u = __builtin_amdgcn_exp2f(fminf(acc[fc][r] * g2[fc][r], 120.0f));
        float p = u * inv[r];
        __builtin_nontemporal_store(p, Ab + (size_t)rl * NN + col);
        int rloc = hi * 4 + r;
        int byte = (rloc * 64 + (fc * 16 + lm) * 2) ^ ((rloc & 7) << 4);
        *(u16*)((char*)pw + byte) = f2b(p);
      }
    }
    if (c < 23) {
#pragma unroll
      for (int fc = 0; fc < 2; ++fc)
#pragma unroll
        for (int r = 0; r < 4; ++r) g2[fc][r] = gnxt[fc][r];
    }
    bf16x8 pa;
    {
      int byte = (lm * 64 + hi * 16) ^ ((lm & 7) << 4);
      pa = __builtin_bit_cast(bf16x8, *(const u16x8*)((const char*)pw + byte));
    }
    const u16* vb = vs[c & 1];
#pragma unroll
    for (int fc = 0; fc < 8; ++fc) {
      int row = fc * 16 + lm;
      int byte = (row * 64 + hi * 16) ^ ((row & 7) << 4);
      bf16x8 b = __builtin_bit_cast(bf16x8, *(const u16x8*)((const char*)vb + byte));
      tacc[fc] = __builtin_amdgcn_mfma_f32_16x16x32_bf16(pa, b, tacc[fc], 0, 0, 0);
    }
    lds_barrier();
  }

  // ---- fc1 fused epilogue: o1[b][n][d][24] = t @ W_fc1^T + b_fc1 (per-wave LDS) ----
  u16* ts = (u16*)ks + w * 2048;   // 4 KB per wave: 16 rows x 128 cols bf16, swizzled
#pragma unroll
  for (int fc = 0; fc < 8; ++fc)
#pragma unroll
    for (int r = 0; r < 4; ++r) {
      int row = hi * 4 + r, col = fc * 16 + lm;
      int byte = (row * 256 + col * 2) ^ ((row & 7) << 4);
      *(u16*)((char*)ts + byte) = f2b(tacc[fc][r]);
    }
  f32x4 of[2] = {};
#pragma unroll
  for (int kk = 0; kk < 4; ++kk) {
    int byte = (lm * 256 + kk * 64 + hi * 16) ^ ((lm & 7) << 4);
    bf16x8 tf = __builtin_bit_cast(bf16x8, *(const u16x8*)((const char*)ts + byte));
#pragma unroll
    for (int g = 0; g < 2; ++g) {
      bf16x8 wf = __builtin_bit_cast(bf16x8,
          *(const u16x8*)(w1h + (size_t)(g * 16 + lm) * 128 + kk * 32 + hi * 8));
      of[g] = __builtin_amdgcn_mfma_f32_16x16x32_bf16(tf, wf, of[g], 0, 0, 0);
    }
  }
  int bi = bd >> 5, di = bd & 31;
#pragma unroll
  for (int g = 0; g < 2; ++g) {
    int pp = g * 16 + lm;
    if (pp < 24) {
      float bb = b_fc1[pp];
#pragma unroll
      for (int r = 0; r < 4; ++r) {
        int n = m0 + w * 16 + hi * 4 + r;
        __builtin_nontemporal_store(of[g][r] + bb,
            o1 + ((size_t)(bi * NN + n) * 32 + di) * 24 + pp);
      }
    }
  }
}

// ---------------- final: fc2 mix over d (o1 contiguous per (b,n)) ----------------
__global__ __launch_bounds__(256) void k_final2(const float* __restrict__ o1, const float* __restrict__ W_fc2,
                                                const float* __restrict__ b_fc2, float* __restrict__ out) {
  __shared__ float ol[2][768];
  __shared__ float w2[96];
  int t = threadIdx.x, half = t >> 7, tl = t & 127;
  int b = blockIdx.x / 384, np = blockIdx.x % 384;
  int n = np * 2 + half;
  const float* src = o1 + (size_t)(b * NN + n) * 768;
  if (t < 96) w2[t] = W_fc2[t];
  for (int i = tl; i < 192; i += 128)
    *(float4*)&ol[half][i * 4] = *(const float4*)(src + i * 4);
  __syncthreads();
  if (tl < 72) {
    int c = tl / 24, pp = tl % 24;
    float acc = b_fc2[c];
#pragma unroll
    for (int d = 0; d < 32; ++d) acc = fmaf(w2[c * 32 + d], ol[half][d * 24 + pp], acc);
    out[(((size_t)b * 3 + c) * NN + n) * 24 + pp] = acc;
  }
}

extern "C" void kernel_launch(void* const* d_in, const int* in_sizes, int n_in,
                              void* d_out, int out_size, void* d_ws, size_t ws_size,
                              hipStream_t stream) {
  (void)in_sizes; (void)n_in; (void)out_size; (void)ws_size;
  const float* x     = (const float*)d_in[1];
  const float* csta  = (const float*)d_in[2];
  const float* cpan  = (const float*)d_in[3];
  const float* Wq    = (const float*)d_in[4];
  const float* bq    = (const float*)d_in[5];
  const float* Wk    = (const float*)d_in[6];
  const float* bk    = (const float*)d_in[7];
  const float* Wv    = (const float*)d_in[8];
  const float* bv    = (const float*)d_in[9];
  const float* W_sta = (const float*)d_in[10];
  const float* b_sta = (const float*)d_in[11];
  const float* W_n1  = (const float*)d_in[12];
  const float* b_n1  = (const float*)d_in[13];
  const float* W_n2  = (const float*)d_in[14];
  const float* b_n2  = (const float*)d_in[15];
  const float* dsc   = (const float*)d_in[16];
  const float* W_fc1 = (const float*)d_in[17];
  const float* b_fc1 = (const float*)d_in[18];
  const float* W_fc2 = (const float*)d_in[19];
  const float* b_fc2 = (const float*)d_in[20];

  float* out  = (float*)d_out;
  float* Aout = out + OUT_OFF_A;
  float* geo  = out + OUT_OFF_GEO;

  float* ws   = (float*)d_ws;
  float* cn   = ws + WS_CN;
  float* nv1  = ws + WS_NV1;
  float* nv2  = ws + WS_NV2;
  float* geoS = ws + WS_GEOS;
  u16*   wh   = (u16*)(ws + WS_WH);
  u16*   w1h  = (u16*)(ws + WS_W1H);
  u16*   qh   = (u16*)(ws + WS_QH);
  u16*   kh   = (u16*)(ws + WS_KH);
  u16*   vT   = (u16*)(ws + WS_VT);
  float* o1   = ws + WS_O1;

  k_prepcvt<<<77, 256, 0, stream>>>(cpan, csta, ws, Wq, Wk, Wv, W_fc1, wh, w1h);
  k_nodes<<<768, 64, 0, stream>>>(cn, W_sta, b_sta, W_n1, b_n1, W_n2, b_n2, nv1, nv2);
  k_geo<<<(NN * NN + 255) / 256, 256, 0, stream>>>(nv1, nv2, cn, dsc, geo, geoS);

  k_qkv<<<768, 256, 0, stream>>>(x, wh, bq, bk, bv, qh, kh, vT);
  k_attn<<<dim3(BD, 12), 256, 0, stream>>>(qh, kh, vT, geoS, w1h, b_fc1, Aout, o1);
  k_final2<<<1536, 256, 0, stream>>>(o1, W_fc2, b_fc2, out);
}